// Round 13
// baseline (481.031 us; speedup 1.0000x reference)
//
#include <hip/hip_runtime.h>
#include <hip/hip_bf16.h>

#define NTOK   4096
#define DMODEL 1024
#define DFF    4096
#define NEXP   8
#define TOPK   2
#define BM 128
#define BN 128
#define BK 64
#define NSLOT   (NTOK*TOPK)            // 8192
#define MAXSLOT (NSLOT + NEXP*BM)      // 9216
#define MAXTILE (MAXSLOT/BM)           // 72 = 8 XCDs * 9

typedef __attribute__((ext_vector_type(8))) short bf16x8;
typedef __attribute__((ext_vector_type(8))) unsigned short u16x8;
typedef __attribute__((ext_vector_type(4))) float f32x4;

__device__ __forceinline__ unsigned short f2bf(float f){
    union { float f; unsigned int u; } v; v.f = f;
    unsigned int r = (v.u + 0x7fffu + ((v.u >> 16) & 1u)) >> 16;
    return (unsigned short)r;
}

__device__ __forceinline__ void gload16(const unsigned short* g, unsigned short* l){
    __builtin_amdgcn_global_load_lds(
        (const __attribute__((address_space(1))) void*)g,
        (__attribute__((address_space(3))) void*)l,
        16, 0, 0);
}

// ------ merged fp32 [R][C] -> bf16 [C][R] transpose-convert, fp32 LDS ------
__global__ __launch_bounds__(256) void k_transpose_convert2(const float* __restrict__ W1,
                                                            const float* __restrict__ W2,
                                                            unsigned short* __restrict__ W1t,
                                                            unsigned short* __restrict__ W2t)
{
    __shared__ float tile[64][65];
    int z = blockIdx.z;
    const float* src; unsigned short* dst; int R, C, r0, c0;
    if(z < 8){
        src = W1  + (size_t)z * DMODEL * DFF;
        dst = W1t + (size_t)z * DMODEL * DFF;
        R = DMODEL; C = DFF;
        r0 = blockIdx.y * 64; c0 = blockIdx.x * 64;
    } else {
        src = W2  + (size_t)(z-8) * DFF * DMODEL;
        dst = W2t + (size_t)(z-8) * DFF * DMODEL;
        R = DFF; C = DMODEL;
        r0 = blockIdx.x * 64; c0 = blockIdx.y * 64;
    }
    int t = threadIdx.x;
    int tr  = t >> 4;          // 0..15
    int tc4 = (t & 15) * 4;    // 0..60
    #pragma unroll
    for(int i=0;i<4;i++){
        float4 v = *(const float4*)&src[(size_t)(r0 + tr + i*16)*C + c0 + tc4];
        tile[tc4+0][tr + i*16] = v.x;
        tile[tc4+1][tr + i*16] = v.y;
        tile[tc4+2][tr + i*16] = v.z;
        tile[tc4+3][tr + i*16] = v.w;
    }
    __syncthreads();
    int cr = t >> 3;           // 0..31
    int rb = (t & 7) * 8;      // 0..56
    #pragma unroll
    for(int i=0;i<2;i++){
        int c = cr + i*32;
        u16x8 o;
        #pragma unroll
        for(int q=0;q<8;q++) o[q] = f2bf(tile[c][rb + q]);
        *(u16x8*)&dst[(size_t)(c0 + c)*R + r0 + rb] = o;
    }
}

// ---------------- gating (+ fused x convert + out zero-init) ----------------
__global__ __launch_bounds__(256) void k_gate(const float* __restrict__ x,
                                              const float* __restrict__ Wg,
                                              const float* __restrict__ bg,
                                              unsigned short* __restrict__ Xb,
                                              float* __restrict__ out,
                                              int* __restrict__ token_e,
                                              float* __restrict__ token_w,
                                              int* __restrict__ cnt)
{
    int tid = threadIdx.x;
    const float4* xs = (const float4*)x + (size_t)blockIdx.x * 1024;
    ushort4* xd = (ushort4*)Xb + (size_t)blockIdx.x * 1024;
    float4* oz = (float4*)out + (size_t)blockIdx.x * 1024;
    float4 z4 = {0.f,0.f,0.f,0.f};
    #pragma unroll
    for(int rep=0;rep<4;rep++){
        float4 v = xs[rep*256 + tid];
        ushort4 o; o.x=f2bf(v.x); o.y=f2bf(v.y); o.z=f2bf(v.z); o.w=f2bf(v.w);
        xd[rep*256 + tid] = o;
        oz[rep*256 + tid] = z4;           // zero the fused-combine accumulator rows
    }

    int wid = tid >> 6, lane = tid & 63;
    int t = blockIdx.x * 4 + wid;
    const float* xr = x + (size_t)t * DMODEL;
    float pe[NEXP];
    #pragma unroll
    for(int e=0;e<NEXP;e++) pe[e] = 0.f;
    for(int i=0;i<DMODEL/64;i++){
        int d = i*64 + lane;
        float xv = xr[d];
        const float* wr = Wg + (size_t)d * NEXP;
        #pragma unroll
        for(int e=0;e<NEXP;e++) pe[e] += xv * wr[e];
    }
    #pragma unroll
    for(int off=32; off>0; off>>=1){
        #pragma unroll
        for(int e=0;e<NEXP;e++) pe[e] += __shfl_xor(pe[e], off);
    }
    if(lane == 0){
        float lg[NEXP], mx = -1e30f;
        #pragma unroll
        for(int e=0;e<NEXP;e++){ lg[e] = pe[e] + bg[e]; mx = fmaxf(mx, lg[e]); }
        float pr[NEXP];
        #pragma unroll
        for(int e=0;e<NEXP;e++) pr[e] = expf(lg[e] - mx);
        int e0 = 0; float p0 = pr[0];
        #pragma unroll
        for(int e=1;e<NEXP;e++) if(pr[e] > p0){ p0 = pr[e]; e0 = e; }
        int e1 = -1; float p1 = -1.f;
        #pragma unroll
        for(int e=0;e<NEXP;e++) if(e != e0 && pr[e] > p1){ p1 = pr[e]; e1 = e; }
        float dn = p0 + p1;
        token_e[2*t]   = e0; token_w[2*t]   = p0/dn;
        token_e[2*t+1] = e1; token_w[2*t+1] = p1/dn;
        atomicAdd(&cnt[e0], 1); atomicAdd(&cnt[e1], 1);
    }
}

// ---------------- prefix: tile table + global cursor init + pad prefill (1 block) ----------------
__global__ __launch_bounds__(256) void k_prefix(const int* __restrict__ cnt,
                                                int* __restrict__ tile_e,
                                                int* __restrict__ tile_row0,
                                                int* __restrict__ tile_valid,
                                                int* __restrict__ cursor,
                                                int* __restrict__ slot_token)
{
    int tid = threadIdx.x;
    if(tid == 0){
        int off = 0, nt = 0;
        for(int e=0;e<NEXP;e++){
            cursor[e] = off;
            int c = cnt[e];
            for(int r=0;r<c;r+=BM){
                tile_e[nt] = e; tile_row0[nt] = off + r;
                tile_valid[nt] = (c - r < BM) ? (c - r) : BM;
                nt++;
            }
            off += ((c + BM - 1)/BM)*BM;
        }
        for(int i=nt;i<MAXTILE;i++){ tile_e[i]=0; tile_row0[i]=0; tile_valid[i]=0; }
    }
    for(int s=tid; s<MAXSLOT; s+=256) slot_token[s] = 0;  // safe gather addr for pad rows
}

// ---------------- scatter: 32 blocks, global cursor atomics ----------------
__global__ __launch_bounds__(256) void k_scatter(const int* __restrict__ token_e,
                                                 const float* __restrict__ token_w,
                                                 int* __restrict__ cursor,
                                                 int* __restrict__ slot_token,
                                                 float* __restrict__ slot_w)
{
    int i = blockIdx.x*256 + threadIdx.x;
    int e = token_e[i];
    int s = atomicAdd(&cursor[e], 1);
    slot_token[s] = i >> 1;
    slot_w[s] = token_w[i];
}

// ---------------- grouped GEMM tile kernel (R8/R12-measured-best, FROZEN) ----------------
// A: bf16, lda == K. GATHER: A row r -> slot_token[row0+r]. else A row = row0+r.
// B: bf16 [E][N][K] (pre-transposed).
// GELU: OutH[slot][N] = gelu(acc+bias).  else: atomicAdd fp32 into outF[token][col] of
// slot_w*(acc+bias) — fused combine.
template<bool GATHER, bool GELU>
__global__ __launch_bounds__(256, 3) void k_gemm(const unsigned short* __restrict__ A,
                                                 const unsigned short* __restrict__ Bw,
                                                 const float* __restrict__ bias,
                                                 const int* __restrict__ tile_e,
                                                 const int* __restrict__ tile_row0,
                                                 const int* __restrict__ tile_valid,
                                                 const int* __restrict__ slot_token,
                                                 const float* __restrict__ slot_w,
                                                 unsigned short* __restrict__ OutH,
                                                 float* __restrict__ outF,
                                                 int K, int N)
{
    int xb = blockIdx.x;
    int tid = (xb & 7) * (MAXTILE/8) + (xb >> 3);   // XCD-chunked bijective swizzle (72 = 8*9)
    int valid = tile_valid[tid];
    if(valid == 0) return;
    int e = tile_e[tid];
    int row0 = tile_row0[tid];
    int n0 = blockIdx.y * BN;
    const unsigned short* Be = Bw + (size_t)e * N * K;

    __shared__ unsigned short As[BM*BK];
    __shared__ unsigned short Bs[BN*BK];

    int t = threadIdx.x;
    int lane = t & 63;
    int wid = t >> 6;
    int wr = wid >> 1, wc = wid & 1;

    // staging: thread t, issue i stages LDS chunk p = i*256+t (16B chunks)
    // row r = i*32 + (t>>3), phys chunk c = t&7; content = global chunk c ^ (r&7)
    int srow = t >> 3;                      // 0..31
    int csw  = (t & 7) ^ (srow & 7);        // swizzled source chunk
    const unsigned short* arow[4];
    const unsigned short* brow[4];
    #pragma unroll
    for(int i=0;i<4;i++){
        int r = i*32 + srow;
        size_t aoff;
        if(GATHER) aoff = (size_t)slot_token[row0 + r] * (size_t)K;
        else       aoff = (size_t)(row0 + r) * (size_t)K;
        arow[i] = A  + aoff + csw*8;
        brow[i] = Be + (size_t)(n0 + r)*K + csw*8;
    }
    unsigned short* alds = As + (size_t)t * 8;
    unsigned short* blds = Bs + (size_t)t * 8;

    f32x4 acc[4][4];
    #pragma unroll
    for(int m=0;m<4;m++)
        #pragma unroll
        for(int n=0;n<4;n++)
            acc[m][n] = (f32x4){0.f,0.f,0.f,0.f};

    int rl = lane & 15;
    int g  = lane >> 4;
    int rx = rl & 7;

    for(int k0=0;k0<K;k0+=BK){
        __syncthreads();   // previous compute done before LDS overwrite
        #pragma unroll
        for(int i=0;i<4;i++){
            gload16(arow[i] + k0, alds + i*2048);
            gload16(brow[i] + k0, blds + i*2048);
        }
        __syncthreads();   // compiler drains vmcnt(0) before barrier -> tile ready

        #pragma unroll
        for(int kb=0;kb<2;kb++){
            int sw = ((kb*4 + g) ^ rx) * 8;   // proven conflict-free swizzled chunk offset
            bf16x8 af[4], bfv[4];
            #pragma unroll
            for(int m=0;m<4;m++) af[m]  = *(const bf16x8*)&As[(wr*64 + m*16 + rl)*BK + sw];
            #pragma unroll
            for(int n=0;n<4;n++) bfv[n] = *(const bf16x8*)&Bs[(wc*64 + n*16 + rl)*BK + sw];
            #pragma unroll
            for(int m=0;m<4;m++)
                #pragma unroll
                for(int n=0;n<4;n++)
                    acc[m][n] = __builtin_amdgcn_mfma_f32_16x16x32_bf16(af[m], bfv[n], acc[m][n], 0, 0, 0);
        }
    }

    const float* be = bias + (size_t)e * N;
    #pragma unroll
    for(int m=0;m<4;m++){
        int rb = wr*64 + m*16 + g*4;
        #pragma unroll
        for(int j=0;j<4;j++){
            int r = rb + j;
            if(r >= valid) continue;
            size_t grow = (size_t)(row0 + r);
            if(GELU){
                #pragma unroll
                for(int n=0;n<4;n++){
                    int col = n0 + wc*64 + n*16 + rl;
                    float v = acc[m][n][j] + be[col];
                    v = 0.5f * v * (1.f + erff(v * 0.70710678118654752f));
                    OutH[grow * (size_t)N + col] = f2bf(v);
                }
            } else {
                float wsc = slot_w[grow];
                float* orow = outF + (size_t)slot_token[grow] * DMODEL;
                #pragma unroll
                for(int n=0;n<4;n++){
                    int col = n0 + wc*64 + n*16 + rl;
                    float v = (acc[m][n][j] + be[col]) * wsc;
                    atomicAdd(&orow[col], v);
                }
            }
        }
    }
}

extern "C" void kernel_launch(void* const* d_in, const int* in_sizes, int n_in,
                              void* d_out, int out_size, void* d_ws, size_t ws_size,
                              hipStream_t stream)
{
    const float* x  = (const float*)d_in[0];
    const float* W1 = (const float*)d_in[1];
    const float* b1 = (const float*)d_in[2];
    const float* W2 = (const float*)d_in[3];
    const float* b2 = (const float*)d_in[4];
    const float* Wg = (const float*)d_in[5];
    const float* bg = (const float*)d_in[6];
    float* out = (float*)d_out;

    char* p = (char*)d_ws;
    auto alloc = [&](size_t bytes)->char*{
        char* r = p; p += (bytes + 255) & ~(size_t)255; return r;
    };
    unsigned short* W1t = (unsigned short*)alloc((size_t)NEXP*DFF*DMODEL*2);   // [E][DFF][DMODEL]
    unsigned short* W2t = (unsigned short*)alloc((size_t)NEXP*DMODEL*DFF*2);   // [E][DMODEL][DFF]
    unsigned short* Xb  = (unsigned short*)alloc((size_t)NTOK*DMODEL*2);
    unsigned short* H   = (unsigned short*)alloc((size_t)MAXSLOT*DFF*2);
    int*   slot_token = (int*)alloc(MAXSLOT*4);
    float* slot_w     = (float*)alloc(MAXSLOT*4);
    int*   token_e    = (int*)alloc(NSLOT*4);
    float* token_w    = (float*)alloc(NSLOT*4);
    int*   cnt        = (int*)alloc(64);
    int*   cursor     = (int*)alloc(64);
    int*   tile_e     = (int*)alloc(MAXTILE*4);
    int*   tile_row0  = (int*)alloc(MAXTILE*4);
    int*   tile_valid = (int*)alloc(MAXTILE*4);
    (void)ws_size; (void)in_sizes; (void)n_in; (void)out_size;

    hipMemsetAsync(cnt, 0, 64, stream);
    k_gate<<<NTOK/4, 256, 0, stream>>>(x, Wg, bg, Xb, out, token_e, token_w, cnt);
    k_transpose_convert2<<<dim3(DFF/64, DMODEL/64, 16), 256, 0, stream>>>(W1, W2, W1t, W2t);
    k_prefix<<<1, 256, 0, stream>>>(cnt, tile_e, tile_row0, tile_valid, cursor, slot_token);
    k_scatter<<<NSLOT/256, 256, 0, stream>>>(token_e, token_w, cursor, slot_token, slot_w);
    // GEMM1: X[slot gather] x W1t -> H (gelu).  grid 72 x 32, K=1024
    k_gemm<true, true ><<<dim3(MAXTILE, DFF/BN), 256, 0, stream>>>(
        Xb, W1t, b1, tile_e, tile_row0, tile_valid, slot_token, slot_w, H, nullptr,
        DMODEL, DFF);
    // GEMM2: H x W2t -> out (atomic fused combine).  grid 72 x 8, K=4096
    k_gemm<false,false><<<dim3(MAXTILE, DMODEL/BN), 256, 0, stream>>>(
        H,  W2t, b2, tile_e, tile_row0, tile_valid, slot_token, slot_w, nullptr, out,
        DFF, DMODEL);
}

// Round 14
// 428.492 us; speedup vs baseline: 1.1226x; 1.1226x over previous
//
#include <hip/hip_runtime.h>
#include <hip/hip_bf16.h>

#define NTOK   4096
#define DMODEL 1024
#define DFF    4096
#define NEXP   8
#define TOPK   2
#define BM 128
#define BN 128
#define BK 64
#define NSLOT   (NTOK*TOPK)            // 8192
#define MAXSLOT (NSLOT + NEXP*BM)      // 9216
#define MAXTILE (MAXSLOT/BM)           // 72 = 8 XCDs * 9
#define NWTILE  8192                   // 64x64 tiles per weight tensor (8 experts)

typedef __attribute__((ext_vector_type(8))) short bf16x8;
typedef __attribute__((ext_vector_type(8))) unsigned short u16x8;
typedef __attribute__((ext_vector_type(4))) float f32x4;

__device__ __forceinline__ unsigned short f2bf(float f){
    union { float f; unsigned int u; } v; v.f = f;
    unsigned int r = (v.u + 0x7fffu + ((v.u >> 16) & 1u)) >> 16;
    return (unsigned short)r;
}

__device__ __forceinline__ void gload16(const unsigned short* g, unsigned short* l){
    __builtin_amdgcn_global_load_lds(
        (const __attribute__((address_space(1))) void*)g,
        (__attribute__((address_space(3))) void*)l,
        16, 0, 0);
}

// ---- proven 64x64 fp32-LDS transpose-convert tile: dst[c0+c][r0+r] = bf16(src[r0+r][c0+c]) ----
__device__ __forceinline__ void transpose_tile64(const float* __restrict__ src,
                                                 unsigned short* __restrict__ dst,
                                                 int R, int C, int r0, int c0,
                                                 float (*tile)[65])
{
    int t = threadIdx.x;
    int tr  = t >> 4;          // 0..15
    int tc4 = (t & 15) * 4;    // 0..60
    #pragma unroll
    for(int i=0;i<4;i++){
        float4 v = *(const float4*)&src[(size_t)(r0 + tr + i*16)*C + c0 + tc4];
        tile[tc4+0][tr + i*16] = v.x;
        tile[tc4+1][tr + i*16] = v.y;
        tile[tc4+2][tr + i*16] = v.z;
        tile[tc4+3][tr + i*16] = v.w;
    }
    __syncthreads();
    int cr = t >> 3;           // 0..31
    int rb = (t & 7) * 8;      // 0..56
    #pragma unroll
    for(int i=0;i<2;i++){
        int c = cr + i*32;
        u16x8 o;
        #pragma unroll
        for(int q=0;q<8;q++) o[q] = f2bf(tile[c][rb + q]);
        *(u16x8*)&dst[(size_t)(c0 + c)*R + r0 + rb] = o;
    }
    __syncthreads();
}

// ---------------- fused: gating (+x convert + out zero) ∥ W1 transpose-convert ----------------
// grid 3072: x%3==0 -> gate block (1024), else -> W1-transpose worker (2048, 4 tiles each)
__global__ __launch_bounds__(256) void k_gate_w1t(const float* __restrict__ x,
                                                  const float* __restrict__ Wg,
                                                  const float* __restrict__ bg,
                                                  const float* __restrict__ W1,
                                                  unsigned short* __restrict__ Xb,
                                                  unsigned short* __restrict__ W1t,
                                                  float* __restrict__ out,
                                                  int* __restrict__ token_e,
                                                  float* __restrict__ token_w,
                                                  int* __restrict__ cnt)
{
    __shared__ float tile[64][65];
    int bx = blockIdx.x;
    if(bx % 3 != 0){
        int w = bx - bx/3 - 1;                 // 0..2047
        for(int t2 = w; t2 < NWTILE; t2 += 2048){
            int z  = t2 >> 10;                 // expert
            int rem = t2 & 1023;
            int rt = rem >> 6;                 // 0..15  (DMODEL/64 src-row tiles)
            int ct = rem & 63;                 // 0..63  (DFF/64 src-col tiles)
            transpose_tile64(W1 + (size_t)z*DMODEL*DFF, W1t + (size_t)z*DMODEL*DFF,
                             DMODEL, DFF, rt*64, ct*64, tile);
        }
        return;
    }
    int b = bx / 3;                            // gate block 0..1023
    int tid = threadIdx.x;
    const float4* xs = (const float4*)x + (size_t)b * 1024;
    ushort4* xd = (ushort4*)Xb + (size_t)b * 1024;
    float4* oz = (float4*)out + (size_t)b * 1024;
    float4 z4 = {0.f,0.f,0.f,0.f};
    #pragma unroll
    for(int rep=0;rep<4;rep++){
        float4 v = xs[rep*256 + tid];
        ushort4 o; o.x=f2bf(v.x); o.y=f2bf(v.y); o.z=f2bf(v.z); o.w=f2bf(v.w);
        xd[rep*256 + tid] = o;
        oz[rep*256 + tid] = z4;                // zero the fused-combine accumulator rows
    }

    int wid = tid >> 6, lane = tid & 63;
    int t = b * 4 + wid;
    const float* xr = x + (size_t)t * DMODEL;
    float pe[NEXP];
    #pragma unroll
    for(int e=0;e<NEXP;e++) pe[e] = 0.f;
    for(int i=0;i<DMODEL/64;i++){
        int d = i*64 + lane;
        float xv = xr[d];
        const float* wr = Wg + (size_t)d * NEXP;
        #pragma unroll
        for(int e=0;e<NEXP;e++) pe[e] += xv * wr[e];
    }
    #pragma unroll
    for(int off=32; off>0; off>>=1){
        #pragma unroll
        for(int e=0;e<NEXP;e++) pe[e] += __shfl_xor(pe[e], off);
    }
    if(lane == 0){
        float lg[NEXP], mx = -1e30f;
        #pragma unroll
        for(int e=0;e<NEXP;e++){ lg[e] = pe[e] + bg[e]; mx = fmaxf(mx, lg[e]); }
        float pr[NEXP];
        #pragma unroll
        for(int e=0;e<NEXP;e++) pr[e] = expf(lg[e] - mx);
        int e0 = 0; float p0 = pr[0];
        #pragma unroll
        for(int e=1;e<NEXP;e++) if(pr[e] > p0){ p0 = pr[e]; e0 = e; }
        int e1 = -1; float p1 = -1.f;
        #pragma unroll
        for(int e=0;e<NEXP;e++) if(e != e0 && pr[e] > p1){ p1 = pr[e]; e1 = e; }
        float dn = p0 + p1;
        token_e[2*t]   = e0; token_w[2*t]   = p0/dn;
        token_e[2*t+1] = e1; token_w[2*t+1] = p1/dn;
        atomicAdd(&cnt[e0], 1); atomicAdd(&cnt[e1], 1);
    }
}

// ---------------- prefix: tile table + global cursor init + pad prefill (1 block) ----------------
__global__ __launch_bounds__(256) void k_prefix(const int* __restrict__ cnt,
                                                int* __restrict__ tile_e,
                                                int* __restrict__ tile_row0,
                                                int* __restrict__ tile_valid,
                                                int* __restrict__ cursor,
                                                int* __restrict__ slot_token)
{
    int tid = threadIdx.x;
    if(tid == 0){
        int off = 0, nt = 0;
        for(int e=0;e<NEXP;e++){
            cursor[e] = off;
            int c = cnt[e];
            for(int r=0;r<c;r+=BM){
                tile_e[nt] = e; tile_row0[nt] = off + r;
                tile_valid[nt] = (c - r < BM) ? (c - r) : BM;
                nt++;
            }
            off += ((c + BM - 1)/BM)*BM;
        }
        for(int i=nt;i<MAXTILE;i++){ tile_e[i]=0; tile_row0[i]=0; tile_valid[i]=0; }
    }
    for(int s=tid; s<MAXSLOT; s+=256) slot_token[s] = 0;  // safe gather addr for pad rows
}

// ---------------- scatter: 32 blocks, global cursor atomics ----------------
__global__ __launch_bounds__(256) void k_scatter(const int* __restrict__ token_e,
                                                 const float* __restrict__ token_w,
                                                 int* __restrict__ cursor,
                                                 int* __restrict__ slot_token,
                                                 float* __restrict__ slot_w)
{
    int i = blockIdx.x*256 + threadIdx.x;
    int e = token_e[i];
    int s = atomicAdd(&cursor[e], 1);
    slot_token[s] = i >> 1;
    slot_w[s] = token_w[i];
}

// ---------------- grouped GEMM tile kernel (R8/R12 FROZEN loop) + optional fused W2 transpose ----------------
// FUSET: grid y=40; y in {4,9,...,39} -> W2-transpose worker (576 total, ~14 tiles each);
// other 32 y-rows are the GEMM N-blocks (n = y - (y+1)/5).
template<bool GATHER, bool GELU, bool FUSET>
__global__ __launch_bounds__(256, 3) void k_gemm(const unsigned short* __restrict__ A,
                                                 const unsigned short* __restrict__ Bw,
                                                 const float* __restrict__ bias,
                                                 const int* __restrict__ tile_e,
                                                 const int* __restrict__ tile_row0,
                                                 const int* __restrict__ tile_valid,
                                                 const int* __restrict__ slot_token,
                                                 const float* __restrict__ slot_w,
                                                 unsigned short* __restrict__ OutH,
                                                 float* __restrict__ outF,
                                                 const float* __restrict__ Wsrc,
                                                 unsigned short* __restrict__ Wdst,
                                                 int K, int N)
{
    __shared__ __align__(16) unsigned short SM[BM*BK + BN*BK];   // 32 KB
    unsigned short* As = SM;
    unsigned short* Bs = SM + BM*BK;

    int y = blockIdx.y;
    if(FUSET && ((y+1) % 5) == 0){
        float (*tile)[65] = (float(*)[65])SM;                    // 16.6 KB alias
        int w = blockIdx.x * 8 + (y/5);                          // 0..575
        for(int t2 = w; t2 < NWTILE; t2 += 576){
            int z  = t2 >> 10;
            int rem = t2 & 1023;
            int rt = rem >> 4;                                   // 0..63 (DFF/64 src-row tiles)
            int ct = rem & 15;                                   // 0..15 (DMODEL/64 src-col tiles)
            transpose_tile64(Wsrc + (size_t)z*DFF*DMODEL, Wdst + (size_t)z*DFF*DMODEL,
                             DFF, DMODEL, rt*64, ct*64, tile);
        }
        return;
    }

    int xb = blockIdx.x;
    int tid = (xb & 7) * (MAXTILE/8) + (xb >> 3);   // XCD-chunked bijective swizzle (72 = 8*9)
    int valid = tile_valid[tid];
    if(valid == 0) return;
    int e = tile_e[tid];
    int row0 = tile_row0[tid];
    int n0 = (FUSET ? (y - (y+1)/5) : y) * BN;
    const unsigned short* Be = Bw + (size_t)e * N * K;

    int t = threadIdx.x;
    int lane = t & 63;
    int wid = t >> 6;
    int wr = wid >> 1, wc = wid & 1;

    // staging: thread t, issue i stages LDS chunk p = i*256+t (16B chunks)
    // row r = i*32 + (t>>3), phys chunk c = t&7; content = global chunk c ^ (r&7)
    int srow = t >> 3;                      // 0..31
    int csw  = (t & 7) ^ (srow & 7);        // swizzled source chunk
    const unsigned short* arow[4];
    const unsigned short* brow[4];
    #pragma unroll
    for(int i=0;i<4;i++){
        int r = i*32 + srow;
        size_t aoff;
        if(GATHER) aoff = (size_t)slot_token[row0 + r] * (size_t)K;
        else       aoff = (size_t)(row0 + r) * (size_t)K;
        arow[i] = A  + aoff + csw*8;
        brow[i] = Be + (size_t)(n0 + r)*K + csw*8;
    }
    unsigned short* alds = As + (size_t)t * 8;
    unsigned short* blds = Bs + (size_t)t * 8;

    f32x4 acc[4][4];
    #pragma unroll
    for(int m=0;m<4;m++)
        #pragma unroll
        for(int n=0;n<4;n++)
            acc[m][n] = (f32x4){0.f,0.f,0.f,0.f};

    int rl = lane & 15;
    int g  = lane >> 4;
    int rx = rl & 7;

    for(int k0=0;k0<K;k0+=BK){
        __syncthreads();   // previous compute done before LDS overwrite
        #pragma unroll
        for(int i=0;i<4;i++){
            gload16(arow[i] + k0, alds + i*2048);
            gload16(brow[i] + k0, blds + i*2048);
        }
        __syncthreads();   // compiler drains vmcnt(0) before barrier -> tile ready

        #pragma unroll
        for(int kb=0;kb<2;kb++){
            int sw = ((kb*4 + g) ^ rx) * 8;   // proven conflict-free swizzled chunk offset
            bf16x8 af[4], bfv[4];
            #pragma unroll
            for(int m=0;m<4;m++) af[m]  = *(const bf16x8*)&As[(wr*64 + m*16 + rl)*BK + sw];
            #pragma unroll
            for(int n=0;n<4;n++) bfv[n] = *(const bf16x8*)&Bs[(wc*64 + n*16 + rl)*BK + sw];
            #pragma unroll
            for(int m=0;m<4;m++)
                #pragma unroll
                for(int n=0;n<4;n++)
                    acc[m][n] = __builtin_amdgcn_mfma_f32_16x16x32_bf16(af[m], bfv[n], acc[m][n], 0, 0, 0);
        }
    }

    const float* be = bias + (size_t)e * N;
    #pragma unroll
    for(int m=0;m<4;m++){
        int rb = wr*64 + m*16 + g*4;
        #pragma unroll
        for(int j=0;j<4;j++){
            int r = rb + j;
            if(r >= valid) continue;
            size_t grow = (size_t)(row0 + r);
            if(GELU){
                #pragma unroll
                for(int n=0;n<4;n++){
                    int col = n0 + wc*64 + n*16 + rl;
                    float v = acc[m][n][j] + be[col];
                    v = 0.5f * v * (1.f + erff(v * 0.70710678118654752f));
                    OutH[grow * (size_t)N + col] = f2bf(v);
                }
            } else {
                float wsc = slot_w[grow];
                float* orow = outF + (size_t)slot_token[grow] * DMODEL;
                #pragma unroll
                for(int n=0;n<4;n++){
                    int col = n0 + wc*64 + n*16 + rl;
                    float v = (acc[m][n][j] + be[col]) * wsc;
                    atomicAdd(&orow[col], v);
                }
            }
        }
    }
}

extern "C" void kernel_launch(void* const* d_in, const int* in_sizes, int n_in,
                              void* d_out, int out_size, void* d_ws, size_t ws_size,
                              hipStream_t stream)
{
    const float* x  = (const float*)d_in[0];
    const float* W1 = (const float*)d_in[1];
    const float* b1 = (const float*)d_in[2];
    const float* W2 = (const float*)d_in[3];
    const float* b2 = (const float*)d_in[4];
    const float* Wg = (const float*)d_in[5];
    const float* bg = (const float*)d_in[6];
    float* out = (float*)d_out;

    char* p = (char*)d_ws;
    auto alloc = [&](size_t bytes)->char*{
        char* r = p; p += (bytes + 255) & ~(size_t)255; return r;
    };
    unsigned short* W1t = (unsigned short*)alloc((size_t)NEXP*DFF*DMODEL*2);   // [E][DFF][DMODEL]
    unsigned short* W2t = (unsigned short*)alloc((size_t)NEXP*DMODEL*DFF*2);   // [E][DMODEL][DFF]
    unsigned short* Xb  = (unsigned short*)alloc((size_t)NTOK*DMODEL*2);
    unsigned short* H   = (unsigned short*)alloc((size_t)MAXSLOT*DFF*2);
    int*   slot_token = (int*)alloc(MAXSLOT*4);
    float* slot_w     = (float*)alloc(MAXSLOT*4);
    int*   token_e    = (int*)alloc(NSLOT*4);
    float* token_w    = (float*)alloc(NSLOT*4);
    int*   cnt        = (int*)alloc(64);
    int*   cursor     = (int*)alloc(64);
    int*   tile_e     = (int*)alloc(MAXTILE*4);
    int*   tile_row0  = (int*)alloc(MAXTILE*4);
    int*   tile_valid = (int*)alloc(MAXTILE*4);
    (void)ws_size; (void)in_sizes; (void)n_in; (void)out_size;

    hipMemsetAsync(cnt, 0, 64, stream);
    // gate ∥ W1-transpose (gate's 42 MB hides under W1T's 201 MB)
    k_gate_w1t<<<3072, 256, 0, stream>>>(x, Wg, bg, W1, Xb, W1t, out,
                                         token_e, token_w, cnt);
    k_prefix<<<1, 256, 0, stream>>>(cnt, tile_e, tile_row0, tile_valid, cursor, slot_token);
    k_scatter<<<NSLOT/256, 256, 0, stream>>>(token_e, token_w, cursor, slot_token, slot_w);
    // GEMM1 (X gather x W1t -> H, gelu) ∥ W2-transpose (hidden in GEMM1's BW headroom).
    // grid 72 x 40: 32 y-rows GEMM N-blocks + 8 y-rows (576 blocks) transpose workers.
    k_gemm<true, true, true ><<<dim3(MAXTILE, 40), 256, 0, stream>>>(
        Xb, W1t, b1, tile_e, tile_row0, tile_valid, slot_token, slot_w, H, nullptr,
        W2, W2t, DMODEL, DFF);
    // GEMM2: H x W2t -> out (atomic fused combine).  grid 72 x 8, K=4096
    k_gemm<false,false,false><<<dim3(MAXTILE, DMODEL/BN), 256, 0, stream>>>(
        H,  W2t, b2, tile_e, tile_row0, tile_valid, slot_token, slot_w, nullptr, out,
        nullptr, nullptr, DFF, DMODEL);
}